// Round 1
// baseline (303.912 us; speedup 1.0000x reference)
//
#include <hip/hip_runtime.h>
#include <hip/hip_bf16.h>
#include <math.h>

#define NPOS 147456  // 384*384
#define NSEQ 384

typedef __attribute__((ext_vector_type(4))) float f32x4;
typedef __attribute__((ext_vector_type(8))) short bf16x8;
typedef __attribute__((ext_vector_type(4))) short s16x4;

__device__ __forceinline__ unsigned short f2bf(float f){
  union { float f; unsigned u; } v; v.f = f;
  unsigned r = v.u + 0x7FFFu + ((v.u >> 16) & 1u);
  return (unsigned short)(r >> 16);
}
__device__ __forceinline__ float bf2f(unsigned short h){
  union { unsigned u; float f; } v; v.u = ((unsigned)h) << 16;
  return v.f;
}
__device__ __forceinline__ float sigmoidf(float x){
  return 1.0f / (1.0f + __expf(-x));
}

// ---------------- weight fp32 -> bf16 convert ----------------
__global__ void wconv(const float* __restrict__ src, unsigned short* __restrict__ dst, int n){
  int i = blockIdx.x * 256 + threadIdx.x;
  if (i < n) dst[i] = f2bf(src[i]);
}

// ---------------- k1: LN(x) + g_in/p_in/g_out projections ----------------
// Block: 256 threads, 64 positions. Outputs a_t/b_t/g_t in [channel][pos] layout (bf16).
__global__ __launch_bounds__(256) void k1_ln_proj(
    const float* __restrict__ x,
    const float* __restrict__ ln_w, const float* __restrict__ ln_b,
    const unsigned short* __restrict__ wg,   // [256][128] bf16
    const unsigned short* __restrict__ wp,   // [256][128] bf16
    const unsigned short* __restrict__ wgo,  // [128][128] bf16
    unsigned short* __restrict__ a_t,        // [128][NPOS]
    unsigned short* __restrict__ b_t,        // [128][NPOS]
    unsigned short* __restrict__ g_t)        // [128][NPOS]
{
  __shared__ unsigned short xn[64][128];   // 16 KB, bf16 LN output
  __shared__ float psum[64][4];
  __shared__ float psq[64][4];
  __shared__ float smean[64];
  __shared__ float srstd[64];

  const int tid  = threadIdx.x;
  const int posb = blockIdx.x * 64;
  const int r = tid >> 2, q = tid & 3;

  // load 32 fp32 of row r (quarter q), accumulate partial stats
  const float* xr = x + (size_t)(posb + r) * 128 + q * 32;
  float v[32];
  float s = 0.f, s2 = 0.f;
  #pragma unroll
  for (int j = 0; j < 8; ++j){
    f32x4 t4 = *(const f32x4*)(xr + j * 4);
    #pragma unroll
    for (int m = 0; m < 4; ++m){ float f = t4[m]; v[j*4+m] = f; s += f; s2 += f*f; }
  }
  psum[r][q] = s; psq[r][q] = s2;
  __syncthreads();
  if (tid < 64){
    float ss = psum[tid][0] + psum[tid][1] + psum[tid][2] + psum[tid][3];
    float qq = psq [tid][0] + psq [tid][1] + psq [tid][2] + psq [tid][3];
    float m  = ss * (1.f/128.f);
    float var = qq * (1.f/128.f) - m * m;
    smean[tid] = m;
    srstd[tid] = rsqrtf(var + 1e-5f);
  }
  __syncthreads();
  {
    float m = smean[r], rs = srstd[r];
    #pragma unroll
    for (int j = 0; j < 32; ++j){
      int k = q * 32 + j;
      float xv = (v[j] - m) * rs * ln_w[k] + ln_b[k];
      xn[r][k] = f2bf(xv);
    }
  }
  __syncthreads();

  // MFMA: wave w owns rows [w*16, w*16+16)
  const int wid = tid >> 6, lane = tid & 63;
  const int lrow = lane & 15, kh = lane >> 4;     // kh in 0..3
  bf16x8 afrag[4];
  #pragma unroll
  for (int kk = 0; kk < 4; ++kk)
    afrag[kk] = *(const bf16x8*)&xn[wid*16 + lrow][kk*32 + kh*8];

  const size_t posg = (size_t)posb + wid*16 + kh*4;   // base pos of this lane's 4 outputs

  // g_in / p_in : 16 col-tiles of 16 over e=0..255 (paired)
  for (int et = 0; et < 16; ++et){
    int col = et * 16 + lrow;
    const unsigned short* wgp = wg + col * 128 + kh * 8;
    const unsigned short* wpp = wp + col * 128 + kh * 8;
    f32x4 accg = {0.f,0.f,0.f,0.f};
    f32x4 accp = {0.f,0.f,0.f,0.f};
    #pragma unroll
    for (int kk = 0; kk < 4; ++kk){
      bf16x8 bg = *(const bf16x8*)(wgp + kk * 32);
      bf16x8 bp = *(const bf16x8*)(wpp + kk * 32);
      accg = __builtin_amdgcn_mfma_f32_16x16x32_bf16(afrag[kk], bg, accg, 0, 0, 0);
      accp = __builtin_amdgcn_mfma_f32_16x16x32_bf16(afrag[kk], bp, accp, 0, 0, 0);
    }
    unsigned short outv[4];
    #pragma unroll
    for (int j = 0; j < 4; ++j)
      outv[j] = f2bf(sigmoidf(accg[j]) * accp[j]);
    unsigned short* dst = (col < 128) ? (a_t + (size_t)col * NPOS + posg)
                                      : (b_t + (size_t)(col - 128) * NPOS + posg);
    *(s16x4*)dst = *(s16x4*)outv;   // 4 consecutive positions, 8B store
  }

  // g_out : 8 col-tiles over e=0..127, store sigmoid
  for (int et = 0; et < 8; ++et){
    int col = et * 16 + lrow;
    const unsigned short* wq = wgo + col * 128 + kh * 8;
    f32x4 acc = {0.f,0.f,0.f,0.f};
    #pragma unroll
    for (int kk = 0; kk < 4; ++kk){
      bf16x8 bq = *(const bf16x8*)(wq + kk * 32);
      acc = __builtin_amdgcn_mfma_f32_16x16x32_bf16(afrag[kk], bq, acc, 0, 0, 0);
    }
    unsigned short outv[4];
    #pragma unroll
    for (int j = 0; j < 4; ++j)
      outv[j] = f2bf(sigmoidf(acc[j]));
    *(s16x4*)(g_t + (size_t)col * NPOS + posg) = *(s16x4*)outv;
  }
}

// ---------------- k2: triangle einsum, batched per channel d ----------------
// C_d[i,j] = sum_k A_d[i,k] * B_d[j,k]; A=a_t[d], B=b_t[d], N=384, tile 128x128, K-step 32
#define K2PAD 56
__global__ __launch_bounds__(256) void k2_tri(
    const unsigned short* __restrict__ a_t,
    const unsigned short* __restrict__ b_t,
    unsigned short* __restrict__ t_t)
{
  __shared__ unsigned short As[128][K2PAD];
  __shared__ unsigned short Bs[128][K2PAD];

  const int d  = blockIdx.z;
  const int i0 = blockIdx.y * 128;
  const int j0 = blockIdx.x * 128;
  const unsigned short* Ab = a_t + (size_t)d * NPOS;
  const unsigned short* Bb = b_t + (size_t)d * NPOS;

  const int tid = threadIdx.x;
  const int wid = tid >> 6, lane = tid & 63;
  const int wr = wid >> 1, wc = wid & 1;
  const int lrow = lane & 15, kh = (lane >> 4) * 8;

  f32x4 acc[4][4];
  #pragma unroll
  for (int r = 0; r < 4; ++r)
    #pragma unroll
    for (int c = 0; c < 4; ++c)
      acc[r][c] = (f32x4){0.f,0.f,0.f,0.f};

  const int sr = tid >> 1, sc = (tid & 1) * 16;

  for (int k0 = 0; k0 < NSEQ; k0 += 32){
    bf16x8 va0 = *(const bf16x8*)(Ab + (size_t)(i0 + sr) * NSEQ + k0 + sc);
    bf16x8 va1 = *(const bf16x8*)(Ab + (size_t)(i0 + sr) * NSEQ + k0 + sc + 8);
    bf16x8 vb0 = *(const bf16x8*)(Bb + (size_t)(j0 + sr) * NSEQ + k0 + sc);
    bf16x8 vb1 = *(const bf16x8*)(Bb + (size_t)(j0 + sr) * NSEQ + k0 + sc + 8);
    __syncthreads();
    *(bf16x8*)&As[sr][sc]     = va0;
    *(bf16x8*)&As[sr][sc + 8] = va1;
    *(bf16x8*)&Bs[sr][sc]     = vb0;
    *(bf16x8*)&Bs[sr][sc + 8] = vb1;
    __syncthreads();

    bf16x8 af[4], bfr[4];
    #pragma unroll
    for (int r = 0; r < 4; ++r)
      af[r] = *(const bf16x8*)&As[wr*64 + r*16 + lrow][kh];
    #pragma unroll
    for (int c = 0; c < 4; ++c)
      bfr[c] = *(const bf16x8*)&Bs[wc*64 + c*16 + lrow][kh];
    #pragma unroll
    for (int r = 0; r < 4; ++r)
      #pragma unroll
      for (int c = 0; c < 4; ++c)
        acc[r][c] = __builtin_amdgcn_mfma_f32_16x16x32_bf16(af[r], bfr[c], acc[r][c], 0, 0, 0);
  }

  unsigned short* Tb = t_t + (size_t)d * NPOS;
  #pragma unroll
  for (int r = 0; r < 4; ++r){
    int i = i0 + wr*64 + r*16 + (lane >> 4) * 4;
    #pragma unroll
    for (int c = 0; c < 4; ++c){
      int j = j0 + wc*64 + c*16 + lrow;
      #pragma unroll
      for (int jj = 0; jj < 4; ++jj)
        Tb[(size_t)(i + jj) * NSEQ + j] = f2bf(acc[r][c][jj]);
    }
  }
}

// ---------------- k3: LN(t) over d + out-projection + gate ----------------
// Block: 256 threads, 128 positions x all 128 channels.
#define K3PAD 136
__global__ __launch_bounds__(256) void k3_out(
    const unsigned short* __restrict__ t_t,   // [128][NPOS]
    const unsigned short* __restrict__ g_t,   // [128][NPOS], post-sigmoid
    const float* __restrict__ ln_w, const float* __restrict__ ln_b,
    const unsigned short* __restrict__ wpo,   // [128][128] bf16
    float* __restrict__ out)                  // [NPOS][128] fp32
{
  __shared__ unsigned short traw[128][K3PAD]; // [d][pos] staging; later reused for g [e][pos]
  __shared__ unsigned short lnt [128][K3PAD]; // [pos][d] LN output
  __shared__ float psum[128][2];
  __shared__ float psq [128][2];
  __shared__ float smean[128];
  __shared__ float srs  [128];

  const int tid = threadIdx.x;
  const int p0  = blockIdx.x * 128;

  // stage t tile: [d][pos]
  {
    int d = tid >> 1, c0 = (tid & 1) * 64;
    const unsigned short* src = t_t + (size_t)d * NPOS + p0 + c0;
    #pragma unroll
    for (int j = 0; j < 8; ++j)
      *(bf16x8*)&traw[d][c0 + j*8] = *(const bf16x8*)(src + j*8);
  }
  __syncthreads();

  // LN stats: 2 threads per position
  const int pos = tid & 127, h = tid >> 7;
  {
    float s = 0.f, s2 = 0.f;
    #pragma unroll 8
    for (int d = h*64; d < h*64 + 64; ++d){
      float f = bf2f(traw[d][pos]);
      s += f; s2 += f*f;
    }
    psum[pos][h] = s; psq[pos][h] = s2;
  }
  __syncthreads();
  if (tid < 128){
    float ss = psum[tid][0] + psum[tid][1];
    float qq = psq [tid][0] + psq [tid][1];
    float m  = ss * (1.f/128.f);
    float var = qq * (1.f/128.f) - m * m;
    smean[tid] = m;
    srs[tid]   = rsqrtf(var + 1e-5f);
  }
  __syncthreads();
  {
    float m = smean[pos], rs = srs[pos];
    #pragma unroll 8
    for (int d = h*64; d < h*64 + 64; ++d){
      float f = (bf2f(traw[d][pos]) - m) * rs * ln_w[d] + ln_b[d];
      lnt[pos][d] = f2bf(f);
    }
  }
  __syncthreads();

  // restage g tile into traw: [e][pos]
  {
    int e = tid >> 1, c0 = (tid & 1) * 64;
    const unsigned short* src = g_t + (size_t)e * NPOS + p0 + c0;
    #pragma unroll
    for (int j = 0; j < 8; ++j)
      *(bf16x8*)&traw[e][c0 + j*8] = *(const bf16x8*)(src + j*8);
  }
  __syncthreads();

  // MFMA: M=128 pos, N=128 e, K=128. Wave w: rows w*32..w*32+32 (2 frags) x 8 col-tiles
  const int wid = tid >> 6, lane = tid & 63;
  const int lrow = lane & 15, kh = (lane >> 4) * 8;

  bf16x8 af[2][4];
  #pragma unroll
  for (int r = 0; r < 2; ++r)
    #pragma unroll
    for (int kk = 0; kk < 4; ++kk)
      af[r][kk] = *(const bf16x8*)&lnt[wid*32 + r*16 + lrow][kk*32 + kh];

  for (int cf = 0; cf < 8; ++cf){
    int e = cf * 16 + lrow;
    const unsigned short* wq = wpo + e * 128 + kh;
    bf16x8 bfr[4];
    #pragma unroll
    for (int kk = 0; kk < 4; ++kk)
      bfr[kk] = *(const bf16x8*)(wq + kk * 32);
    f32x4 acc[2];
    acc[0] = (f32x4){0.f,0.f,0.f,0.f};
    acc[1] = (f32x4){0.f,0.f,0.f,0.f};
    #pragma unroll
    for (int kk = 0; kk < 4; ++kk){
      acc[0] = __builtin_amdgcn_mfma_f32_16x16x32_bf16(af[0][kk], bfr[kk], acc[0], 0, 0, 0);
      acc[1] = __builtin_amdgcn_mfma_f32_16x16x32_bf16(af[1][kk], bfr[kk], acc[1], 0, 0, 0);
    }
    #pragma unroll
    for (int r = 0; r < 2; ++r){
      int prow = wid*32 + r*16 + (lane >> 4) * 4;
      #pragma unroll
      for (int jj = 0; jj < 4; ++jj){
        float g = bf2f(traw[e][prow + jj]);
        out[(size_t)(p0 + prow + jj) * 128 + e] = g * acc[r][jj];
      }
    }
  }
}

// ---------------- launch ----------------
extern "C" void kernel_launch(void* const* d_in, const int* in_sizes, int n_in,
                              void* d_out, int out_size, void* d_ws, size_t ws_size,
                              hipStream_t stream) {
  (void)in_sizes; (void)n_in; (void)out_size; (void)ws_size;
  const float* x   = (const float*)d_in[0];
  const float* niw = (const float*)d_in[1];
  const float* nib = (const float*)d_in[2];
  const float* wgi = (const float*)d_in[3];
  const float* wpi = (const float*)d_in[4];
  const float* wgo = (const float*)d_in[5];
  const float* now = (const float*)d_in[6];
  const float* nob = (const float*)d_in[7];
  const float* wpo = (const float*)d_in[8];
  float* out = (float*)d_out;

  unsigned short* a_t   = (unsigned short*)d_ws;
  unsigned short* b_t   = a_t + (size_t)128 * NPOS;
  unsigned short* g_t   = b_t + (size_t)128 * NPOS;
  unsigned short* t_t   = g_t + (size_t)128 * NPOS;
  unsigned short* wgi_b = t_t + (size_t)128 * NPOS;
  unsigned short* wpi_b = wgi_b + 256 * 128;
  unsigned short* wgo_b = wpi_b + 256 * 128;
  unsigned short* wpo_b = wgo_b + 128 * 128;

  wconv<<<(256*128 + 255)/256, 256, 0, stream>>>(wgi, wgi_b, 256*128);
  wconv<<<(256*128 + 255)/256, 256, 0, stream>>>(wpi, wpi_b, 256*128);
  wconv<<<(128*128 + 255)/256, 256, 0, stream>>>(wgo, wgo_b, 128*128);
  wconv<<<(128*128 + 255)/256, 256, 0, stream>>>(wpo, wpo_b, 128*128);

  k1_ln_proj<<<NPOS/64, 256, 0, stream>>>(x, niw, nib, wgi_b, wpi_b, wgo_b, a_t, b_t, g_t);

  dim3 g2(3, 3, 128);
  k2_tri<<<g2, 256, 0, stream>>>(a_t, b_t, t_t);

  k3_out<<<NPOS/128, 256, 0, stream>>>(t_t, g_t, now, nob, wpo_b, out);
}

// Round 2
// 184.781 us; speedup vs baseline: 1.6447x; 1.6447x over previous
//
#include <hip/hip_runtime.h>
#include <hip/hip_bf16.h>
#include <math.h>

#define NPOS 147456  // 384*384
#define NSEQ 384

typedef __attribute__((ext_vector_type(4))) float f32x4;
typedef __attribute__((ext_vector_type(8))) short bf16x8;
typedef __attribute__((ext_vector_type(4))) short s16x4;

__device__ __forceinline__ unsigned short f2bf(float f){
  union { float f; unsigned u; } v; v.f = f;
  unsigned r = v.u + 0x7FFFu + ((v.u >> 16) & 1u);
  return (unsigned short)(r >> 16);
}
__device__ __forceinline__ float bf2f(unsigned short h){
  union { unsigned u; float f; } v; v.u = ((unsigned)h) << 16;
  return v.f;
}
__device__ __forceinline__ float sigmoidf(float x){
  return 1.0f / (1.0f + __expf(-x));
}

// ---------------- weight fp32 -> bf16, swizzled to MFMA B-frag order ----------
// dst[((et*4+kk)*64 + lane)*8 + j] = bf16(src[(et*16 + (lane&15))*128 + kk*32 + (lane>>4)*8 + j])
__global__ void wswz(const float* __restrict__ src, unsigned short* __restrict__ dst, int netiles){
  int i = blockIdx.x * 256 + threadIdx.x;
  int n = netiles * 2048;
  if (i >= n) return;
  int j    = i & 7;
  int lane = (i >> 3) & 63;
  int kk   = (i >> 9) & 3;
  int et   = i >> 11;
  int lrow = lane & 15, kh = lane >> 4;
  int srci = (et*16 + lrow)*128 + kk*32 + kh*8 + j;
  dst[i] = f2bf(src[srci]);
}

// ---------------- k1: LN(x) + g_in/p_in/g_out projections ----------------
// Block: 256 threads (4 waves), 128 positions. Wave w owns pos [w*32, w*32+32).
// Outputs a_t/b_t/g_t in [channel][pos] bf16 layout with coalesced stores.
__global__ __launch_bounds__(256, 4) void k1_ln_proj(
    const float* __restrict__ x,
    const float* __restrict__ ln_w, const float* __restrict__ ln_b,
    const unsigned short* __restrict__ wg_sw,   // 16 et-tiles, swizzled
    const unsigned short* __restrict__ wp_sw,   // 16 et-tiles, swizzled
    const unsigned short* __restrict__ wgo_sw,  // 8 et-tiles, swizzled
    unsigned short* __restrict__ a_t,           // [128][NPOS]
    unsigned short* __restrict__ b_t,           // [128][NPOS]
    unsigned short* __restrict__ g_t)           // [128][NPOS]
{
  __shared__ unsigned short xn[128][128];     // XOR-swizzled (col8 ^= row&7), 32 KB
  __shared__ unsigned short obuf[4][16][40];  // per-wave out staging, 5 KB

  const int tid  = threadIdx.x;
  const int posb = blockIdx.x * 128;
  const int lane = tid & 63;
  const int wid  = tid >> 6;

  // ---- LN: 2 groups of 64 rows, 4 threads per row, stats via shfl ----
  const int rql = tid >> 2;   // row within group
  const int q   = tid & 3;    // quarter of the 128 channels
  #pragma unroll
  for (int rr = 0; rr < 2; ++rr){
    int row = rr*64 + rql;
    const float* xr = x + (size_t)(posb + row) * 128 + q * 32;
    float v[32]; float s = 0.f, s2 = 0.f;
    #pragma unroll
    for (int j2 = 0; j2 < 8; ++j2){
      f32x4 t4 = *(const f32x4*)(xr + j2*4);
      #pragma unroll
      for (int m = 0; m < 4; ++m){ float f = t4[m]; v[j2*4+m] = f; s += f; s2 += f*f; }
    }
    s  += __shfl_xor(s, 1);  s  += __shfl_xor(s, 2);
    s2 += __shfl_xor(s2, 1); s2 += __shfl_xor(s2, 2);
    float mean = s * (1.f/128.f);
    float rstd = rsqrtf(s2 * (1.f/128.f) - mean*mean + 1e-5f);
    int sw = (row & 7) * 8;
    #pragma unroll
    for (int c = 0; c < 4; ++c){
      unsigned short tmp[8];
      #pragma unroll
      for (int j2 = 0; j2 < 8; ++j2){
        int k = q*32 + c*8 + j2;
        tmp[j2] = f2bf((v[c*8+j2] - mean) * rstd * ln_w[k] + ln_b[k]);
      }
      *(bf16x8*)&xn[row][(q*32 + c*8) ^ sw] = *(const bf16x8*)tmp;
    }
  }
  __syncthreads();

  // ---- MFMA phase: wave w rows w*32..w*32+31 (2 row frags) ----
  const int lrow = lane & 15, kh = lane >> 4;
  bf16x8 afrag[2][4];
  #pragma unroll
  for (int r = 0; r < 2; ++r){
    int row = wid*32 + r*16 + lrow;
    int sw = (row & 7) * 8;
    #pragma unroll
    for (int kk = 0; kk < 4; ++kk)
      afrag[r][kk] = *(const bf16x8*)&xn[row][(kk*32 + kh*8) ^ sw];
  }

  unsigned short (*ob)[40] = obuf[wid];
  const int scol = lane >> 2;         // store: col within tile
  const int spos = (lane & 3) * 8;    // store: pos offset
  const size_t posw = (size_t)posb + wid*32;

  // g_in (sigmoid) * p_in : 16 paired col-tiles over e = 0..255
  for (int et = 0; et < 16; ++et){
    const unsigned short* wgb = wg_sw + et*2048 + lane*8;
    const unsigned short* wpb = wp_sw + et*2048 + lane*8;
    f32x4 accg[2] = {{0.f,0.f,0.f,0.f},{0.f,0.f,0.f,0.f}};
    f32x4 accp[2] = {{0.f,0.f,0.f,0.f},{0.f,0.f,0.f,0.f}};
    #pragma unroll
    for (int kk = 0; kk < 4; ++kk){
      bf16x8 bg = *(const bf16x8*)(wgb + kk*512);
      bf16x8 bp = *(const bf16x8*)(wpb + kk*512);
      accg[0] = __builtin_amdgcn_mfma_f32_16x16x32_bf16(afrag[0][kk], bg, accg[0], 0, 0, 0);
      accg[1] = __builtin_amdgcn_mfma_f32_16x16x32_bf16(afrag[1][kk], bg, accg[1], 0, 0, 0);
      accp[0] = __builtin_amdgcn_mfma_f32_16x16x32_bf16(afrag[0][kk], bp, accp[0], 0, 0, 0);
      accp[1] = __builtin_amdgcn_mfma_f32_16x16x32_bf16(afrag[1][kk], bp, accp[1], 0, 0, 0);
    }
    #pragma unroll
    for (int r = 0; r < 2; ++r){
      unsigned short ov[4];
      #pragma unroll
      for (int j = 0; j < 4; ++j)
        ov[j] = f2bf(sigmoidf(accg[r][j]) * accp[r][j]);
      *(s16x4*)&ob[lrow][r*16 + kh*4] = *(s16x4*)ov;
    }
    // wave-private staging: in-order DS pipe, no barrier needed
    bf16x8 ovv = *(const bf16x8*)&ob[scol][spos];
    int colg = et*16 + scol;
    unsigned short* dst = (colg < 128) ? (a_t + (size_t)colg * NPOS + posw + spos)
                                       : (b_t + (size_t)(colg - 128) * NPOS + posw + spos);
    *(bf16x8*)dst = ovv;
  }

  // g_out : 8 col-tiles over e = 0..127 (sigmoid only)
  for (int et = 0; et < 8; ++et){
    const unsigned short* wqb = wgo_sw + et*2048 + lane*8;
    f32x4 acc2[2] = {{0.f,0.f,0.f,0.f},{0.f,0.f,0.f,0.f}};
    #pragma unroll
    for (int kk = 0; kk < 4; ++kk){
      bf16x8 bq = *(const bf16x8*)(wqb + kk*512);
      acc2[0] = __builtin_amdgcn_mfma_f32_16x16x32_bf16(afrag[0][kk], bq, acc2[0], 0, 0, 0);
      acc2[1] = __builtin_amdgcn_mfma_f32_16x16x32_bf16(afrag[1][kk], bq, acc2[1], 0, 0, 0);
    }
    #pragma unroll
    for (int r = 0; r < 2; ++r){
      unsigned short ov[4];
      #pragma unroll
      for (int j = 0; j < 4; ++j)
        ov[j] = f2bf(sigmoidf(acc2[r][j]));
      *(s16x4*)&ob[lrow][r*16 + kh*4] = *(s16x4*)ov;
    }
    bf16x8 ovv = *(const bf16x8*)&ob[scol][spos];
    *(bf16x8*)(g_t + (size_t)(et*16 + scol) * NPOS + posw + spos) = ovv;
  }
}

// ---------------- k2: triangle einsum, batched per channel d ----------------
// C_d[i,j] = sum_k A_d[i,k] * B_d[j,k]; tile 128x128, K-step 32
#define K2PAD 56
__global__ __launch_bounds__(256) void k2_tri(
    const unsigned short* __restrict__ a_t,
    const unsigned short* __restrict__ b_t,
    unsigned short* __restrict__ t_t)
{
  __shared__ unsigned short As[128][K2PAD];
  __shared__ unsigned short Bs[128][K2PAD];

  const int d  = blockIdx.z;
  const int i0 = blockIdx.y * 128;
  const int j0 = blockIdx.x * 128;
  const unsigned short* Ab = a_t + (size_t)d * NPOS;
  const unsigned short* Bb = b_t + (size_t)d * NPOS;

  const int tid = threadIdx.x;
  const int wid = tid >> 6, lane = tid & 63;
  const int wr = wid >> 1, wc = wid & 1;
  const int lrow = lane & 15, kh = (lane >> 4) * 8;

  f32x4 acc[4][4];
  #pragma unroll
  for (int r = 0; r < 4; ++r)
    #pragma unroll
    for (int c = 0; c < 4; ++c)
      acc[r][c] = (f32x4){0.f,0.f,0.f,0.f};

  const int sr = tid >> 1, sc = (tid & 1) * 16;

  for (int k0 = 0; k0 < NSEQ; k0 += 32){
    bf16x8 va0 = *(const bf16x8*)(Ab + (size_t)(i0 + sr) * NSEQ + k0 + sc);
    bf16x8 va1 = *(const bf16x8*)(Ab + (size_t)(i0 + sr) * NSEQ + k0 + sc + 8);
    bf16x8 vb0 = *(const bf16x8*)(Bb + (size_t)(j0 + sr) * NSEQ + k0 + sc);
    bf16x8 vb1 = *(const bf16x8*)(Bb + (size_t)(j0 + sr) * NSEQ + k0 + sc + 8);
    __syncthreads();
    *(bf16x8*)&As[sr][sc]     = va0;
    *(bf16x8*)&As[sr][sc + 8] = va1;
    *(bf16x8*)&Bs[sr][sc]     = vb0;
    *(bf16x8*)&Bs[sr][sc + 8] = vb1;
    __syncthreads();

    bf16x8 af[4], bfr[4];
    #pragma unroll
    for (int r = 0; r < 4; ++r)
      af[r] = *(const bf16x8*)&As[wr*64 + r*16 + lrow][kh];
    #pragma unroll
    for (int c = 0; c < 4; ++c)
      bfr[c] = *(const bf16x8*)&Bs[wc*64 + c*16 + lrow][kh];
    #pragma unroll
    for (int r = 0; r < 4; ++r)
      #pragma unroll
      for (int c = 0; c < 4; ++c)
        acc[r][c] = __builtin_amdgcn_mfma_f32_16x16x32_bf16(af[r], bfr[c], acc[r][c], 0, 0, 0);
  }

  unsigned short* Tb = t_t + (size_t)d * NPOS;
  #pragma unroll
  for (int r = 0; r < 4; ++r){
    int i = i0 + wr*64 + r*16 + (lane >> 4) * 4;
    #pragma unroll
    for (int c = 0; c < 4; ++c){
      int j = j0 + wc*64 + c*16 + lrow;
      #pragma unroll
      for (int jj = 0; jj < 4; ++jj)
        Tb[(size_t)(i + jj) * NSEQ + j] = f2bf(acc[r][c][jj]);
    }
  }
}

// ---------------- k3: LN(t) over d + out-projection + gate ----------------
#define K3PAD 136
__global__ __launch_bounds__(256) void k3_out(
    const unsigned short* __restrict__ t_t,   // [128][NPOS]
    const unsigned short* __restrict__ g_t,   // [128][NPOS], post-sigmoid
    const float* __restrict__ ln_w, const float* __restrict__ ln_b,
    const unsigned short* __restrict__ wpo_sw, // 8 et-tiles, swizzled
    float* __restrict__ out)                  // [NPOS][128] fp32
{
  __shared__ unsigned short traw[128][K3PAD]; // [d][pos] staging; later reused for g [e][pos]
  __shared__ unsigned short lnt [128][K3PAD]; // [pos][d] LN output
  __shared__ float psum[128][2];
  __shared__ float psq [128][2];
  __shared__ float smean[128];
  __shared__ float srs  [128];

  const int tid = threadIdx.x;
  const int p0  = blockIdx.x * 128;

  // stage t tile: [d][pos]
  {
    int d = tid >> 1, c0 = (tid & 1) * 64;
    const unsigned short* src = t_t + (size_t)d * NPOS + p0 + c0;
    #pragma unroll
    for (int j = 0; j < 8; ++j)
      *(bf16x8*)&traw[d][c0 + j*8] = *(const bf16x8*)(src + j*8);
  }
  __syncthreads();

  const int pos = tid & 127, h = tid >> 7;
  {
    float s = 0.f, s2 = 0.f;
    #pragma unroll 8
    for (int d = h*64; d < h*64 + 64; ++d){
      float f = bf2f(traw[d][pos]);
      s += f; s2 += f*f;
    }
    psum[pos][h] = s; psq[pos][h] = s2;
  }
  __syncthreads();
  if (tid < 128){
    float ss = psum[tid][0] + psum[tid][1];
    float qq = psq [tid][0] + psq [tid][1];
    float m  = ss * (1.f/128.f);
    float var = qq * (1.f/128.f) - m * m;
    smean[tid] = m;
    srs[tid]   = rsqrtf(var + 1e-5f);
  }
  __syncthreads();
  {
    float m = smean[pos], rs = srs[pos];
    #pragma unroll 8
    for (int d = h*64; d < h*64 + 64; ++d){
      float f = (bf2f(traw[d][pos]) - m) * rs * ln_w[d] + ln_b[d];
      lnt[pos][d] = f2bf(f);
    }
  }
  __syncthreads();

  // restage g tile into traw: [e][pos]
  {
    int e = tid >> 1, c0 = (tid & 1) * 64;
    const unsigned short* src = g_t + (size_t)e * NPOS + p0 + c0;
    #pragma unroll
    for (int j = 0; j < 8; ++j)
      *(bf16x8*)&traw[e][c0 + j*8] = *(const bf16x8*)(src + j*8);
  }
  __syncthreads();

  const int wid = tid >> 6, lane = tid & 63;
  const int lrow = lane & 15, kh = (lane >> 4) * 8;

  bf16x8 af[2][4];
  #pragma unroll
  for (int r = 0; r < 2; ++r)
    #pragma unroll
    for (int kk = 0; kk < 4; ++kk)
      af[r][kk] = *(const bf16x8*)&lnt[wid*32 + r*16 + lrow][kk*32 + kh];

  for (int cf = 0; cf < 8; ++cf){
    const unsigned short* wq = wpo_sw + cf*2048 + lane*8;
    bf16x8 bfr[4];
    #pragma unroll
    for (int kk = 0; kk < 4; ++kk)
      bfr[kk] = *(const bf16x8*)(wq + kk*512);
    f32x4 acc[2];
    acc[0] = (f32x4){0.f,0.f,0.f,0.f};
    acc[1] = (f32x4){0.f,0.f,0.f,0.f};
    #pragma unroll
    for (int kk = 0; kk < 4; ++kk){
      acc[0] = __builtin_amdgcn_mfma_f32_16x16x32_bf16(af[0][kk], bfr[kk], acc[0], 0, 0, 0);
      acc[1] = __builtin_amdgcn_mfma_f32_16x16x32_bf16(af[1][kk], bfr[kk], acc[1], 0, 0, 0);
    }
    int e = cf * 16 + lrow;
    #pragma unroll
    for (int r = 0; r < 2; ++r){
      int prow = wid*32 + r*16 + (lane >> 4) * 4;
      #pragma unroll
      for (int jj = 0; jj < 4; ++jj){
        float g = bf2f(traw[e][prow + jj]);
        out[(size_t)(p0 + prow + jj) * 128 + e] = g * acc[r][jj];
      }
    }
  }
}

// ---------------- launch ----------------
extern "C" void kernel_launch(void* const* d_in, const int* in_sizes, int n_in,
                              void* d_out, int out_size, void* d_ws, size_t ws_size,
                              hipStream_t stream) {
  (void)in_sizes; (void)n_in; (void)out_size; (void)ws_size;
  const float* x   = (const float*)d_in[0];
  const float* niw = (const float*)d_in[1];
  const float* nib = (const float*)d_in[2];
  const float* wgi = (const float*)d_in[3];
  const float* wpi = (const float*)d_in[4];
  const float* wgo = (const float*)d_in[5];
  const float* now = (const float*)d_in[6];
  const float* nob = (const float*)d_in[7];
  const float* wpo = (const float*)d_in[8];
  float* out = (float*)d_out;

  unsigned short* a_t   = (unsigned short*)d_ws;
  unsigned short* b_t   = a_t + (size_t)128 * NPOS;
  unsigned short* g_t   = b_t + (size_t)128 * NPOS;
  unsigned short* t_t   = g_t + (size_t)128 * NPOS;
  unsigned short* wgi_s = t_t + (size_t)128 * NPOS;
  unsigned short* wpi_s = wgi_s + 256 * 128;
  unsigned short* wgo_s = wpi_s + 256 * 128;
  unsigned short* wpo_s = wgo_s + 128 * 128;

  wswz<<<(16*2048 + 255)/256, 256, 0, stream>>>(wgi, wgi_s, 16);
  wswz<<<(16*2048 + 255)/256, 256, 0, stream>>>(wpi, wpi_s, 16);
  wswz<<<( 8*2048 + 255)/256, 256, 0, stream>>>(wgo, wgo_s, 8);
  wswz<<<( 8*2048 + 255)/256, 256, 0, stream>>>(wpo, wpo_s, 8);

  k1_ln_proj<<<NPOS/128, 256, 0, stream>>>(x, niw, nib, wgi_s, wpi_s, wgo_s, a_t, b_t, g_t);

  dim3 g2(3, 3, 128);
  k2_tri<<<g2, 256, 0, stream>>>(a_t, b_t, t_t);

  k3_out<<<NPOS/128, 256, 0, stream>>>(t_t, g_t, now, nob, wpo_s, out);
}

// Round 5
// 168.193 us; speedup vs baseline: 1.8069x; 1.0986x over previous
//
#include <hip/hip_runtime.h>
#include <hip/hip_bf16.h>
#include <math.h>

#define NPOS 147456  // 384*384
#define NSEQ 384

typedef __attribute__((ext_vector_type(4))) float f32x4;
typedef __attribute__((ext_vector_type(8))) short bf16x8;
typedef __attribute__((ext_vector_type(4))) short s16x4;

__device__ __forceinline__ unsigned short f2bf(float f){
  union { float f; unsigned u; } v; v.f = f;
  unsigned r = v.u + 0x7FFFu + ((v.u >> 16) & 1u);
  return (unsigned short)(r >> 16);
}
__device__ __forceinline__ float bf2f(unsigned short h){
  union { unsigned u; float f; } v; v.u = ((unsigned)h) << 16;
  return v.f;
}
// v_rcp_f32-based sigmoid: bounded (0,1), ~1ulp rcp error
__device__ __forceinline__ float fastsig(float x){
  return __builtin_amdgcn_rcpf(1.0f + __expf(-x));
}
// order-explicit packed bf16 pair: lo -> bits[15:0], hi -> bits[31:16]
__device__ __forceinline__ unsigned pk2(float lo, float hi){
  return (unsigned)f2bf(lo) | ((unsigned)f2bf(hi) << 16);
}

// ---------------- all weights fp32 -> bf16, MFMA B-frag order, one launch ----
__global__ void wswz_all(const float* __restrict__ wgi, const float* __restrict__ wpi,
                         const float* __restrict__ wgo, const float* __restrict__ wpo,
                         unsigned short* __restrict__ wgi_s, unsigned short* __restrict__ wpi_s,
                         unsigned short* __restrict__ wgo_s, unsigned short* __restrict__ wpo_s){
  int i = blockIdx.x * 256 + threadIdx.x;   // 48 tiles * 2048 = 98304 threads exactly
  int t = i >> 11;
  int r = i & 2047;
  const float* src; unsigned short* dst; int lt;
  if (t < 16)      { src = wgi; dst = wgi_s; lt = t;      }
  else if (t < 32) { src = wpi; dst = wpi_s; lt = t - 16; }
  else if (t < 40) { src = wgo; dst = wgo_s; lt = t - 32; }
  else             { src = wpo; dst = wpo_s; lt = t - 40; }
  int j = r & 7, lane = (r >> 3) & 63, kk = (r >> 9) & 3;
  int lrow = lane & 15, khh = lane >> 4;
  dst[lt*2048 + r] = f2bf(src[(lt*16 + lrow)*128 + kk*32 + khh*8 + j]);
}

// ---------------- k1: LN(x) + g_in/p_in/g_out projections ----------------
// 256 threads (4 waves), 128 positions/block. Outputs [channel][pos] bf16.
// obuf lives in xn's LDS space (xn dead after afrag extraction).
__global__ __launch_bounds__(256, 3) void k1_ln_proj(
    const float* __restrict__ x,
    const float* __restrict__ ln_w, const float* __restrict__ ln_b,
    const unsigned short* __restrict__ wg_sw,
    const unsigned short* __restrict__ wp_sw,
    const unsigned short* __restrict__ wgo_sw,
    unsigned short* __restrict__ a_t,
    unsigned short* __restrict__ b_t,
    unsigned short* __restrict__ g_t)
{
  __shared__ unsigned short xn[128][128];   // 32 KB; later reused as obuf[2][16][136]
  unsigned short (*obuf)[16][136] = reinterpret_cast<unsigned short(*)[16][136]>(&xn[0][0]);

  const int tid  = threadIdx.x;
  const int posb = blockIdx.x * 128;
  const int lane = tid & 63;
  const int wid  = tid >> 6;

  // ---- LN: 4 threads per row, stats via shfl ----
  const int rql = tid >> 2;
  const int q   = tid & 3;
  #pragma unroll
  for (int rr = 0; rr < 2; ++rr){
    int row = rr*64 + rql;
    const float* xr = x + (size_t)(posb + row) * 128 + q * 32;
    float v[32]; float s = 0.f, s2 = 0.f;
    #pragma unroll
    for (int j2 = 0; j2 < 8; ++j2){
      f32x4 t4 = *(const f32x4*)(xr + j2*4);
      #pragma unroll
      for (int m = 0; m < 4; ++m){ float f = t4[m]; v[j2*4+m] = f; s += f; s2 += f*f; }
    }
    s  += __shfl_xor(s, 1);  s  += __shfl_xor(s, 2);
    s2 += __shfl_xor(s2, 1); s2 += __shfl_xor(s2, 2);
    float mean = s * (1.f/128.f);
    float rstd = rsqrtf(s2 * (1.f/128.f) - mean*mean + 1e-5f);
    int sw = (row & 7) * 8;
    #pragma unroll
    for (int c = 0; c < 4; ++c){
      float n[8];
      #pragma unroll
      for (int j2 = 0; j2 < 8; ++j2){
        int k = q*32 + c*8 + j2;
        n[j2] = (v[c*8+j2] - mean) * rstd * ln_w[k] + ln_b[k];
      }
      uint4 u;
      u.x = pk2(n[0], n[1]); u.y = pk2(n[2], n[3]);
      u.z = pk2(n[4], n[5]); u.w = pk2(n[6], n[7]);
      *(uint4*)&xn[row][(q*32 + c*8) ^ sw] = u;
    }
  }
  __syncthreads();

  // ---- afrag extraction: wave w rows w*32..w*32+31 ----
  const int lrow = lane & 15, kh = lane >> 4;
  bf16x8 afrag[2][4];
  #pragma unroll
  for (int r = 0; r < 2; ++r){
    int row = wid*32 + r*16 + lrow;
    int sw = (row & 7) * 8;
    #pragma unroll
    for (int kk = 0; kk < 4; ++kk)
      afrag[r][kk] = *(const bf16x8*)&xn[row][(kk*32 + kh*8) ^ sw];
  }
  __syncthreads();   // xn dead -> obuf space live

  const int kh4 = kh * 4;
  const int scl = wid*4 + kh;        // coop-store: this lane's channel within tile
  const int spo = lrow * 8;          // coop-store: pos offset

#define LOADW_PAIR(G, P, et) do { \
    const unsigned short* _wg = wg_sw + (size_t)(et)*2048 + lane*8; \
    const unsigned short* _wp = wp_sw + (size_t)(et)*2048 + lane*8; \
    _Pragma("unroll") \
    for (int kk = 0; kk < 4; ++kk){ \
      G[kk] = *(const bf16x8*)(_wg + kk*512); \
      P[kk] = *(const bf16x8*)(_wp + kk*512); \
    } } while(0)

#define COMPUTE_PAIR(G, P, et) do { \
    f32x4 accg0 = {0.f,0.f,0.f,0.f}, accg1 = {0.f,0.f,0.f,0.f}; \
    f32x4 accp0 = {0.f,0.f,0.f,0.f}, accp1 = {0.f,0.f,0.f,0.f}; \
    _Pragma("unroll") \
    for (int kk = 0; kk < 4; ++kk){ \
      accg0 = __builtin_amdgcn_mfma_f32_16x16x32_bf16(afrag[0][kk], G[kk], accg0, 0, 0, 0); \
      accg1 = __builtin_amdgcn_mfma_f32_16x16x32_bf16(afrag[1][kk], G[kk], accg1, 0, 0, 0); \
      accp0 = __builtin_amdgcn_mfma_f32_16x16x32_bf16(afrag[0][kk], P[kk], accp0, 0, 0, 0); \
      accp1 = __builtin_amdgcn_mfma_f32_16x16x32_bf16(afrag[1][kk], P[kk], accp1, 0, 0, 0); \
    } \
    { uint2 u0, u1; \
      u0.x = pk2(fastsig(accg0[0])*accp0[0], fastsig(accg0[1])*accp0[1]); \
      u0.y = pk2(fastsig(accg0[2])*accp0[2], fastsig(accg0[3])*accp0[3]); \
      u1.x = pk2(fastsig(accg1[0])*accp1[0], fastsig(accg1[1])*accp1[1]); \
      u1.y = pk2(fastsig(accg1[2])*accp1[2], fastsig(accg1[3])*accp1[3]); \
      *(uint2*)&obuf[(et)&1][lrow][wid*32 + kh4]      = u0; \
      *(uint2*)&obuf[(et)&1][lrow][wid*32 + 16 + kh4] = u1; } \
    __syncthreads(); \
    { bf16x8 vv = *(const bf16x8*)&obuf[(et)&1][scl][spo]; \
      int colg = (et)*16 + scl; \
      unsigned short* dst = ((et) < 8) ? (a_t + (size_t)colg * NPOS) \
                                       : (b_t + (size_t)(colg - 128) * NPOS); \
      *(bf16x8*)(dst + posb + spo) = vv; } \
  } while(0)

  {
    bf16x8 gA[4], pA[4], gB[4], pB[4];
    LOADW_PAIR(gA, pA, 0);
    #pragma unroll
    for (int e2 = 0; e2 < 8; ++e2){
      LOADW_PAIR(gB, pB, e2*2 + 1);
      COMPUTE_PAIR(gA, pA, e2*2);
      if (e2 < 7) LOADW_PAIR(gA, pA, e2*2 + 2);
      COMPUTE_PAIR(gB, pB, e2*2 + 1);
    }
  }

#define LOADW_G(Q, et) do { \
    const unsigned short* _wq = wgo_sw + (size_t)(et)*2048 + lane*8; \
    _Pragma("unroll") \
    for (int kk = 0; kk < 4; ++kk) Q[kk] = *(const bf16x8*)(_wq + kk*512); \
  } while(0)

#define COMPUTE_G(Q, et) do { \
    f32x4 a0 = {0.f,0.f,0.f,0.f}, a1 = {0.f,0.f,0.f,0.f}; \
    _Pragma("unroll") \
    for (int kk = 0; kk < 4; ++kk){ \
      a0 = __builtin_amdgcn_mfma_f32_16x16x32_bf16(afrag[0][kk], Q[kk], a0, 0, 0, 0); \
      a1 = __builtin_amdgcn_mfma_f32_16x16x32_bf16(afrag[1][kk], Q[kk], a1, 0, 0, 0); \
    } \
    { uint2 u0, u1; \
      u0.x = pk2(fastsig(a0[0]), fastsig(a0[1])); \
      u0.y = pk2(fastsig(a0[2]), fastsig(a0[3])); \
      u1.x = pk2(fastsig(a1[0]), fastsig(a1[1])); \
      u1.y = pk2(fastsig(a1[2]), fastsig(a1[3])); \
      *(uint2*)&obuf[(et)&1][lrow][wid*32 + kh4]      = u0; \
      *(uint2*)&obuf[(et)&1][lrow][wid*32 + 16 + kh4] = u1; } \
    __syncthreads(); \
    { bf16x8 vv = *(const bf16x8*)&obuf[(et)&1][scl][spo]; \
      *(bf16x8*)(g_t + (size_t)((et)*16 + scl) * NPOS + posb + spo) = vv; } \
  } while(0)

  {
    bf16x8 qA[4], qB[4];
    LOADW_G(qA, 0);
    #pragma unroll
    for (int e2 = 0; e2 < 4; ++e2){
      LOADW_G(qB, e2*2 + 1);
      COMPUTE_G(qA, e2*2);
      if (e2 < 3) LOADW_G(qA, e2*2 + 2);
      COMPUTE_G(qB, e2*2 + 1);
    }
  }
#undef LOADW_PAIR
#undef COMPUTE_PAIR
#undef LOADW_G
#undef COMPUTE_G
}

// ---------------- k2: triangle einsum, batched per channel d ----------------
#define K2PAD 56
__global__ __launch_bounds__(256) void k2_tri(
    const unsigned short* __restrict__ a_t,
    const unsigned short* __restrict__ b_t,
    unsigned short* __restrict__ t_t)
{
  __shared__ unsigned short As[128][K2PAD];
  __shared__ unsigned short Bs[128][K2PAD];

  const int d  = blockIdx.z;
  const int i0 = blockIdx.y * 128;
  const int j0 = blockIdx.x * 128;
  const unsigned short* Ab = a_t + (size_t)d * NPOS;
  const unsigned short* Bb = b_t + (size_t)d * NPOS;

  const int tid = threadIdx.x;
  const int wid = tid >> 6, lane = tid & 63;
  const int wr = wid >> 1, wc = wid & 1;
  const int lrow = lane & 15, kh = (lane >> 4) * 8;

  f32x4 acc[4][4];
  #pragma unroll
  for (int r = 0; r < 4; ++r)
    #pragma unroll
    for (int c = 0; c < 4; ++c)
      acc[r][c] = (f32x4){0.f,0.f,0.f,0.f};

  const int sr = tid >> 1, sc = (tid & 1) * 16;

  for (int k0 = 0; k0 < NSEQ; k0 += 32){
    bf16x8 va0 = *(const bf16x8*)(Ab + (size_t)(i0 + sr) * NSEQ + k0 + sc);
    bf16x8 va1 = *(const bf16x8*)(Ab + (size_t)(i0 + sr) * NSEQ + k0 + sc + 8);
    bf16x8 vb0 = *(const bf16x8*)(Bb + (size_t)(j0 + sr) * NSEQ + k0 + sc);
    bf16x8 vb1 = *(const bf16x8*)(Bb + (size_t)(j0 + sr) * NSEQ + k0 + sc + 8);
    __syncthreads();
    *(bf16x8*)&As[sr][sc]     = va0;
    *(bf16x8*)&As[sr][sc + 8] = va1;
    *(bf16x8*)&Bs[sr][sc]     = vb0;
    *(bf16x8*)&Bs[sr][sc + 8] = vb1;
    __syncthreads();

    bf16x8 af[4], bfr[4];
    #pragma unroll
    for (int r = 0; r < 4; ++r)
      af[r] = *(const bf16x8*)&As[wr*64 + r*16 + lrow][kh];
    #pragma unroll
    for (int c = 0; c < 4; ++c)
      bfr[c] = *(const bf16x8*)&Bs[wc*64 + c*16 + lrow][kh];
    #pragma unroll
    for (int r = 0; r < 4; ++r)
      #pragma unroll
      for (int c = 0; c < 4; ++c)
        acc[r][c] = __builtin_amdgcn_mfma_f32_16x16x32_bf16(af[r], bfr[c], acc[r][c], 0, 0, 0);
  }

  unsigned short* Tb = t_t + (size_t)d * NPOS;
  #pragma unroll
  for (int r = 0; r < 4; ++r){
    int i = i0 + wr*64 + r*16 + (lane >> 4) * 4;
    #pragma unroll
    for (int c = 0; c < 4; ++c){
      int j = j0 + wc*64 + c*16 + lrow;
      #pragma unroll
      for (int jj = 0; jj < 4; ++jj)
        Tb[(size_t)(i + jj) * NSEQ + j] = f2bf(acc[r][c][jj]);
    }
  }
}

// ---------------- k3: LN(t) over d + out-projection + gate ----------------
// regB region is time-multiplexed: stats partials -> lnt [128][136]u16 -> ltile [128][68]f32
#define LNS 136
__global__ __launch_bounds__(256, 3) void k3_out(
    const unsigned short* __restrict__ t_t,
    const unsigned short* __restrict__ g_t,
    const float* __restrict__ ln_w, const float* __restrict__ ln_b,
    const unsigned short* __restrict__ wpo_sw,
    float* __restrict__ out)
{
  __shared__ unsigned short traw[128][136];  // 34816 B: t tile, later g tile
  __shared__ float regB[9024];               // 36096 B
  __shared__ float smean[128], srs[128];

  const int tid = threadIdx.x;
  const int p0  = blockIdx.x * 128;
  const int lane = tid & 63, wid = tid >> 6;

  float* pps = regB;                              // [16][128]
  float* ppq = regB + 2048;                       // [16][128]
  unsigned short* lnt = (unsigned short*)regB;    // [128][LNS]
  float (*ltile)[68] = (float(*)[68])regB;        // [128][68]

  // stage t tile: [d][pos]
  {
    int d = tid >> 1, c0 = (tid & 1) * 64;
    const unsigned short* src = t_t + (size_t)d * NPOS + p0 + c0;
    #pragma unroll
    for (int j = 0; j < 8; ++j)
      *(bf16x8*)&traw[d][c0 + j*8] = *(const bf16x8*)(src + j*8);
  }
  __syncthreads();

  // stats partials: thread = (pg: 8-pos chunk, dh: 8-d chunk), vectorized b128 reads
  const int pg = tid & 15, dh = tid >> 4;
  {
    float s8[8] = {0,0,0,0,0,0,0,0}, q8[8] = {0,0,0,0,0,0,0,0};
    #pragma unroll
    for (int jd = 0; jd < 8; ++jd){
      bf16x8 v = *(const bf16x8*)&traw[dh*8 + jd][pg*8];
      #pragma unroll
      for (int p = 0; p < 8; ++p){
        float f = bf2f((unsigned short)v[p]);
        s8[p] += f; q8[p] += f*f;
      }
    }
    #pragma unroll
    for (int p = 0; p < 8; ++p){
      pps[dh*128 + pg*8 + p] = s8[p];
      ppq[dh*128 + pg*8 + p] = q8[p];
    }
  }
  __syncthreads();
  if (tid < 128){
    float s = 0.f, q = 0.f;
    #pragma unroll
    for (int k = 0; k < 16; ++k){ s += pps[k*128 + tid]; q += ppq[k*128 + tid]; }
    float m = s * (1.f/128.f);
    smean[tid] = m;
    srs[tid]   = rsqrtf(q * (1.f/128.f) - m*m + 1e-5f);
  }
  __syncthreads();

  // normalize -> lnt[pos][d] with in-register transpose (overwrites pps/ppq region)
  {
    float vv[8][8];
    #pragma unroll
    for (int jd = 0; jd < 8; ++jd){
      bf16x8 v = *(const bf16x8*)&traw[dh*8 + jd][pg*8];
      float w = ln_w[dh*8 + jd], bb = ln_b[dh*8 + jd];
      #pragma unroll
      for (int p = 0; p < 8; ++p)
        vv[jd][p] = (bf2f((unsigned short)v[p]) - smean[pg*8+p]) * srs[pg*8+p] * w + bb;
    }
    #pragma unroll
    for (int p = 0; p < 8; ++p){
      uint4 u;
      u.x = pk2(vv[0][p], vv[1][p]); u.y = pk2(vv[2][p], vv[3][p]);
      u.z = pk2(vv[4][p], vv[5][p]); u.w = pk2(vv[6][p], vv[7][p]);
      *(uint4*)&lnt[(size_t)(pg*8 + p)*LNS + dh*8] = u;
    }
  }
  __syncthreads();

  // A-fragments from lnt
  const int lrow = lane & 15, kh = (lane >> 4) * 8;
  bf16x8 af[2][4];
  #pragma unroll
  for (int r = 0; r < 2; ++r)
    #pragma unroll
    for (int kk = 0; kk < 4; ++kk)
      af[r][kk] = *(const bf16x8*)&lnt[(size_t)(wid*32 + r*16 + lrow)*LNS + kk*32 + kh];
  __syncthreads();   // lnt dead -> ltile space free

  // restage g tile into traw: [e][pos]
  {
    int e = tid >> 1, c0 = (tid & 1) * 64;
    const unsigned short* src = g_t + (size_t)e * NPOS + p0 + c0;
    #pragma unroll
    for (int j = 0; j < 8; ++j)
      *(bf16x8*)&traw[e][c0 + j*8] = *(const bf16x8*)(src + j*8);
  }
  __syncthreads();

  // out-projection + gate, half the e-range at a time, staged in ltile (f32)
  #pragma unroll
  for (int half = 0; half < 2; ++half){
    #pragma unroll
    for (int cf4 = 0; cf4 < 4; ++cf4){
      int cf = half*4 + cf4;
      const unsigned short* wq = wpo_sw + (size_t)cf*2048 + lane*8;
      bf16x8 bfr[4];
      #pragma unroll
      for (int kk = 0; kk < 4; ++kk)
        bfr[kk] = *(const bf16x8*)(wq + kk*512);
      f32x4 a0 = {0.f,0.f,0.f,0.f}, a1 = {0.f,0.f,0.f,0.f};
      #pragma unroll
      for (int kk = 0; kk < 4; ++kk){
        a0 = __builtin_amdgcn_mfma_f32_16x16x32_bf16(af[0][kk], bfr[kk], a0, 0, 0, 0);
        a1 = __builtin_amdgcn_mfma_f32_16x16x32_bf16(af[1][kk], bfr[kk], a1, 0, 0, 0);
      }
      int e = cf*16 + lrow;
      #pragma unroll
      for (int r = 0; r < 2; ++r){
        f32x4 av = r ? a1 : a0;
        int prow = wid*32 + r*16 + (lane >> 4)*4;
        #pragma unroll
        for (int jj = 0; jj < 4; ++jj){
          float g = bf2f(traw[e][prow + jj]);
          ltile[prow + jj][cf4*16 + lrow] = g * av[jj];
        }
      }
    }
    __syncthreads();
    {
      int pos = tid >> 1, he = tid & 1;
      const float* srcp = &ltile[pos][he*32];
      float* dst = out + (size_t)(p0 + pos)*128 + half*64 + he*32;
      #pragma unroll
      for (int j = 0; j < 8; ++j)
        *(f32x4*)(dst + j*4) = *(const f32x4*)(srcp + j*4);
    }
    __syncthreads();
  }
}

// ---------------- launch ----------------
extern "C" void kernel_launch(void* const* d_in, const int* in_sizes, int n_in,
                              void* d_out, int out_size, void* d_ws, size_t ws_size,
                              hipStream_t stream) {
  (void)in_sizes; (void)n_in; (void)out_size; (void)ws_size;
  const float* x   = (const float*)d_in[0];
  const float* niw = (const float*)d_in[1];
  const float* nib = (const float*)d_in[2];
  const float* wgi = (const float*)d_in[3];
  const float* wpi = (const float*)d_in[4];
  const float* wgo = (const float*)d_in[5];
  const float* now = (const float*)d_in[6];
  const float* nob = (const float*)d_in[7];
  const float* wpo = (const float*)d_in[8];
  float* out = (float*)d_out;

  unsigned short* a_t   = (unsigned short*)d_ws;
  unsigned short* b_t   = a_t + (size_t)128 * NPOS;
  unsigned short* g_t   = b_t + (size_t)128 * NPOS;
  unsigned short* t_t   = g_t + (size_t)128 * NPOS;
  unsigned short* wgi_s = t_t + (size_t)128 * NPOS;
  unsigned short* wpi_s = wgi_s + 256 * 128;
  unsigned short* wgo_s = wpi_s + 256 * 128;
  unsigned short* wpo_s = wgo_s + 128 * 128;

  wswz_all<<<384, 256, 0, stream>>>(wgi, wpi, wgo, wpo, wgi_s, wpi_s, wgo_s, wpo_s);

  k1_ln_proj<<<NPOS/128, 256, 0, stream>>>(x, niw, nib, wgi_s, wpi_s, wgo_s, a_t, b_t, g_t);

  dim3 g2(3, 3, 128);
  k2_tri<<<g2, 256, 0, stream>>>(a_t, b_t, t_t);

  k3_out<<<NPOS/128, 256, 0, stream>>>(t_t, g_t, now, nob, wpo_s, out);
}